// Round 1
// baseline (512.700 us; speedup 1.0000x reference)
//
#include <hip/hip_runtime.h>

// Problem constants (from reference): B=16, S=512, T=16, P=4, G=S/P=128
#define SDIM 512
#define GDIM 128
#define TDIM 16

// K1: per-patch CAM channel 0 + min/max normalization over t.
// Layout: 16 lanes per patch (lane = channel t), 16 patches per 256-thread block.
// top output layout: (b, gi, gj, t) so K2 reads are contiguous in t.
__global__ __launch_bounds__(256) void cam_patch_kernel(const float* __restrict__ inp,
                                                        const float* __restrict__ w3,
                                                        float* __restrict__ top) {
    int n  = blockIdx.x * 16 + (threadIdx.x >> 4);   // patch id, 0..262143
    int tt = threadIdx.x & 15;                        // channel
    int b   = n >> 14;          // / (128*128)
    int rem = n & 16383;
    int gi  = rem >> 7;
    int gj  = rem & 127;

    // lane tt holds weight for k = tt (channel-0 column of the 16x6 block)
    float wlane = w3[n * 96 + tt * 6];

    float v = 0.f;
#pragma unroll
    for (int r = 0; r < 4; ++r) {
        const float* rowp = inp + ((size_t)((b * SDIM + gi * 4 + r) * SDIM + gj * 4) * TDIM) + tt;
#pragma unroll
        for (int c = 0; c < 4; ++c) {
            float wk = __shfl(wlane, r * 4 + c, 16);  // broadcast weight k within patch group
            v += rowp[c * TDIM] * wk;
        }
    }

    // min/max over the 16 channels (16-lane butterfly)
    float mn = v, mx = v;
#pragma unroll
    for (int off = 8; off >= 1; off >>= 1) {
        mn = fminf(mn, __shfl_xor(mn, off, 16));
        mx = fmaxf(mx, __shfl_xor(mx, off, 16));
    }
    float outv = (v - mn) / (mx - mn);   // == (v - min) / max(v - min), fp-monotone identical

    top[((size_t)((b * GDIM + gi) * GDIM + gj) * TDIM) + tt] = outv;
}

// K2: bilinear upsample (G,G)->(S,S), align_corners=True, one block per output row (b,o).
// Stages the two source rows (i0, i0+1) -- contiguous 16 KB -- into LDS.
__global__ __launch_bounds__(256) void upsample_kernel(const float* __restrict__ top,
                                                       float* __restrict__ out) {
    __shared__ float lds[2 * GDIM * TDIM];   // 16 KB

    int b = blockIdx.x >> 9;     // / 512
    int o = blockIdx.x & 511;

    const float scale = 127.0f / 511.0f;
    float ci = (float)o * scale;
    int i0 = (int)ci; if (i0 > GDIM - 2) i0 = GDIM - 2;
    float wi = ci - (float)i0;

    // rows i0 and i0+1 are contiguous in (b,i,j,t) layout -> one contiguous copy
    const float4* src = (const float4*)(top + (size_t)(b * GDIM + i0) * GDIM * TDIM);
    float4* dst = (float4*)lds;
#pragma unroll
    for (int idx = threadIdx.x; idx < 2 * GDIM * TDIM / 4; idx += 256)
        dst[idx] = src[idx];
    __syncthreads();

    size_t obase = (size_t)(b * SDIM + o) * SDIM * TDIM;
#pragma unroll
    for (int m = 0; m < 32; ++m) {
        int idx = m * 256 + threadIdx.x;   // p*16 + tt, 0..8191
        int p  = idx >> 4;
        int tt = idx & 15;
        float cj = (float)p * scale;
        int j0 = (int)cj; if (j0 > GDIM - 2) j0 = GDIM - 2;
        float wj = cj - (float)j0;

        float a = lds[j0 * TDIM + tt];
        float bb = lds[j0 * TDIM + TDIM + tt];
        float c = lds[GDIM * TDIM + j0 * TDIM + tt];
        float d = lds[GDIM * TDIM + j0 * TDIM + TDIM + tt];
        float r0v = a + wj * (bb - a);
        float r1v = c + wj * (d - c);
        out[obase + idx] = r0v + wi * (r1v - r0v);
    }
}

extern "C" void kernel_launch(void* const* d_in, const int* in_sizes, int n_in,
                              void* d_out, int out_size, void* d_ws, size_t ws_size,
                              hipStream_t stream) {
    const float* inp = (const float*)d_in[0];   // (16,512,512,16) fp32
    const float* w3  = (const float*)d_in[1];   // (262144,16,6) fp32
    float* out = (float*)d_out;                 // (16*512*512, 16) fp32
    float* top = (float*)d_ws;                  // (16,128,128,16) fp32 = 16 MB

    // K1: 262144 patches / 16 per block = 16384 blocks
    cam_patch_kernel<<<16384, 256, 0, stream>>>(inp, w3, top);
    // K2: one block per (b, o) output row = 16*512 = 8192 blocks
    upsample_kernel<<<8192, 256, 0, stream>>>(top, out);
}